// Round 27
// baseline (263.919 us; speedup 1.0000x reference)
//
#include <hip/hip_runtime.h>
#include <hip/hip_bf16.h>
#include <cstdint>
#include <cstddef>

// Problem constants
#define S_DIM 2048
#define H_DIM 2048
#define NHEAD 16
#define HD_DIM 128
#define O3    6144   // 3*H
#define BS    4096   // B*S
#define NBH   32     // B*NHEAD

typedef short  s16x4  __attribute__((ext_vector_type(4)));
typedef short  s16x8  __attribute__((ext_vector_type(8)));
typedef __bf16 bf16x8 __attribute__((ext_vector_type(8)));
typedef float  f32x4  __attribute__((ext_vector_type(4)));
typedef float  f32x16 __attribute__((ext_vector_type(16)));

__device__ __forceinline__ unsigned short f2bf(float f) {
  unsigned int b = __float_as_uint(f);
  b += 0x7FFFu + ((b >> 16) & 1u);          // round-to-nearest-even
  return (unsigned short)(b >> 16);
}
__device__ __forceinline__ float bf2f(unsigned short u) {
  return __uint_as_float(((unsigned int)u) << 16);
}
__device__ __forceinline__ bf16x8 load8(const unsigned short* p) {
  s16x8 r = *(const s16x8*)p;
  return __builtin_bit_cast(bf16x8, r);
}
__device__ __forceinline__ f32x4 mfma_bf16(bf16x8 a, bf16x8 b, f32x4 c) {
  return __builtin_amdgcn_mfma_f32_16x16x32_bf16(a, b, c, 0, 0, 0);
}
__device__ __forceinline__ f32x16 mfma32(bf16x8 a, bf16x8 b, f32x16 c) {
  return __builtin_amdgcn_mfma_f32_32x32x16_bf16(a, b, c, 0, 0, 0);
}
__device__ __forceinline__ void gload_lds16(const void* g, void* l) {
  __builtin_amdgcn_global_load_lds(
      (__attribute__((address_space(1))) unsigned int*)g,
      (__attribute__((address_space(3))) unsigned int*)l, 16, 0, 0);
}

// -------------------------------------------------- fused prep (one launch)
__global__ void prep_kernel(const float* __restrict__ hid,
                            const float* __restrict__ wqkv,
                            const float* __restrict__ wo,
                            unsigned short* __restrict__ hid_b,
                            unsigned short* __restrict__ wqkv_b,
                            unsigned short* __restrict__ wo_b,
                            float* __restrict__ cosT,
                            float* __restrict__ sinT) {
  const int nA = 2097152, nB = 3145728, nC = 1048576, nD = 131072;
  const int total = nA + nB + nC + nD;
  int stride = gridDim.x * blockDim.x;
  for (int i = blockIdx.x * blockDim.x + threadIdx.x; i < total; i += stride) {
    if (i < nA + nB + nC) {
      const float* src; unsigned short* dst; int j;
      if (i < nA)            { src = hid;  dst = hid_b;  j = i; }
      else if (i < nA + nB)  { src = wqkv; dst = wqkv_b; j = i - nA; }
      else                   { src = wo;   dst = wo_b;   j = i - nA - nB; }
      float4 v = ((const float4*)src)[j];
      ushort4 o;
      o.x = f2bf(v.x); o.y = f2bf(v.y); o.z = f2bf(v.z); o.w = f2bf(v.w);
      ((ushort4*)dst)[j] = o;
    } else {
      int idx = i - nA - nB - nC;          // 0..131071 = s*64 + d
      int s = idx >> 6, d = idx & 63;
      float inv = expf(-((float)d / 64.0f) * 9.210340371976184f);
      float ang = (float)s * inv;
      float sn, cs;
      sincosf(ang, &sn, &cs);
      cosT[idx] = cs;
      sinT[idx] = sn;
    }
  }
}

// ------------------------------------- QKV GEMM with fused RoPE + V-transpose
// Mainloop = proven gemm3b pipeline (3buf, vmcnt(6)) but with 32x32x16 MFMA:
// same 16 ds_read_b128 per wave/tile, HALF the MFMA instructions (16 vs 32)
// for identical FLOPs, and the 32x32 pipe's ubench ceiling is ~10% higher
// (m119: 2495 vs 2176 TF). A-frag: row lane&31, k (lane>>5)*8+e; C/D:
// col lane&31, row (reg&3)+8(reg>>2)+4(lane>>5) (m74/m101).
// Swizzle: row&7 = (lane&31)&7 is frag-invariant; per-lane column XOR
// hoisted into colx[ks] (4 values); frag delta fr*4096 additive (bits>=12).
__global__ __launch_bounds__(512, 1)
void gemm_qkv_kernel(const unsigned short* __restrict__ A,
                     const unsigned short* __restrict__ Bw,
                     unsigned short* __restrict__ q_r,
                     unsigned short* __restrict__ k_r,
                     unsigned short* __restrict__ v_t,
                     const float* __restrict__ cosT,
                     const float* __restrict__ sinT,
                     int M, int N, int K) {
  __shared__ __align__(16) unsigned short lA[3][128 * 64];   // 3 x 16KB
  __shared__ __align__(16) unsigned short lB[3][256 * 64];   // 3 x 32KB
  const int tid  = threadIdx.x;
  const int wave = tid >> 6, lane = tid & 63;
  const int wm = wave >> 2, wn = wave & 3;       // 2M x 4N wave grid
  const int l31 = lane & 31, hi = lane >> 5;

  // L2-aware XCD map (r11): grid 24(n) x 32(m)
  const int nbx = gridDim.x;
  const int id  = blockIdx.y * nbx + blockIdx.x;
  const int k8 = id & 7, q8 = id >> 3;
  const int ng = q8 >> 5, r8 = q8 & 31;
  const int m_tile = (k8 >> 1) * 8 + (r8 & 7);
  const int n_tile = (k8 & 1) * 12 + ng * 4 + (r8 >> 3);
  const int m0 = m_tile * 128, n0 = n_tile * 256;

  f32x16 acc[2][2];
#pragma unroll
  for (int i = 0; i < 2; ++i)
#pragma unroll
    for (int j = 0; j < 2; ++j)
#pragma unroll
      for (int e = 0; e < 16; ++e) acc[i][j][e] = 0.f;

  const unsigned short* aP[2];
  const unsigned short* bP[4];
  int aD[2], bD[4];
#pragma unroll
  for (int i = 0; i < 2; ++i) {
    int cb = (i * 8 + wave) * 64 + lane;
    int cs = cb ^ ((cb >> 3) & 7);
    aP[i] = A + (size_t)(m0 + (cs >> 3)) * K + (cs & 7) * 8;
    aD[i] = cb * 8;
  }
#pragma unroll
  for (int i = 0; i < 4; ++i) {
    int cb = (i * 8 + wave) * 64 + lane;
    int cs = cb ^ ((cb >> 3) & 7);
    bP[i] = Bw + (size_t)(n0 + (cs >> 3)) * K + (cs & 7) * 8;
    bD[i] = cb * 8;
  }

  auto STAGE = [&](int buf, int t) {
    const int kt = t << 6;
#pragma unroll
    for (int i = 0; i < 2; ++i) gload_lds16(aP[i] + kt, &lA[buf][aD[i]]);
#pragma unroll
    for (int i = 0; i < 4; ++i) gload_lds16(bP[i] + kt, &lB[buf][bD[i]]);
  };

  // hoisted fragment addressing (byte offsets)
  const int rowA = wm * 8192 + l31 * 128;
  const int rowB = wn * 8192 + l31 * 128;
  int colx[4];
#pragma unroll
  for (int ks = 0; ks < 4; ++ks)
    colx[ks] = (ks * 32 + hi * 16) ^ ((l31 & 7) << 4);

  const int NT = K >> 6;
  STAGE(0, 0);
  STAGE(1, 1);
  asm volatile("s_waitcnt vmcnt(6)" ::: "memory");
  asm volatile("s_barrier" ::: "memory");

  for (int t = 0; t < NT; ++t) {
    const int cur = t % 3;
    const char* bA = (const char*)&lA[cur][0] + rowA;
    const char* bB = (const char*)&lB[cur][0] + rowB;

    bf16x8 af[4][2], bfr[4][2];
#pragma unroll
    for (int ks = 0; ks < 4; ++ks) {
      af[ks][0]  = load8((const unsigned short*)(bA + colx[ks]));
      af[ks][1]  = load8((const unsigned short*)(bA + colx[ks] + 4096));
      bfr[ks][0] = load8((const unsigned short*)(bB + colx[ks]));
      bfr[ks][1] = load8((const unsigned short*)(bB + colx[ks] + 4096));
    }

    if (t + 2 < NT) STAGE((t + 2) % 3, t + 2);

    __builtin_amdgcn_s_setprio(1);
#pragma unroll
    for (int ks = 0; ks < 4; ++ks)
#pragma unroll
      for (int fr = 0; fr < 2; ++fr)
#pragma unroll
        for (int fc = 0; fc < 2; ++fc)
          acc[fr][fc] = mfma32(af[ks][fr], bfr[ks][fc], acc[fr][fc]);
    __builtin_amdgcn_s_setprio(0);

    if (t + 2 < NT)
      asm volatile("s_waitcnt vmcnt(6)" ::: "memory");
    else if (t + 1 < NT)
      asm volatile("s_waitcnt vmcnt(0)" ::: "memory");
    asm volatile("s_barrier" ::: "memory");
  }

  // ---- fused epilogue (after final barrier: LDS reuse is safe) ----
  const int g   = n_tile * 4 + wn;
  const int sub = g % 6, hh = g / 6;
  float* slot = (wave < 3) ? (float*)&lA[wave][0]
                           : (float*)&lB[0][0] + (size_t)(wave - 3) * 4096;
  const float* pslot = ((wave ^ 1) < 3)
                           ? (const float*)&lA[wave ^ 1][0]
                           : (const float*)&lB[0][0] + (size_t)((wave ^ 1) - 3) * 4096;

  if (sub < 4) {
    // exchange layout [idx][lane], idx = fr*32 + fc*16 + reg (conflict-free)
#pragma unroll
    for (int fr = 0; fr < 2; ++fr)
#pragma unroll
      for (int fc = 0; fc < 2; ++fc)
#pragma unroll
        for (int reg = 0; reg < 16; ++reg)
          slot[(fr * 32 + fc * 16 + reg) * 64 + lane] = acc[fr][fc][reg];
  } else {
    // transpose layout [d][m ^ ((d&7)<<3)] (bijective per row)
#pragma unroll
    for (int fr = 0; fr < 2; ++fr)
#pragma unroll
      for (int fc = 0; fc < 2; ++fc)
#pragma unroll
        for (int reg = 0; reg < 16; ++reg) {
          int d = fc * 32 + l31;
          int m = fr * 32 + (reg & 3) + 8 * (reg >> 2) + 4 * hi;
          slot[d * 64 + (m ^ ((d & 7) << 3))] = acc[fr][fc][reg];
        }
  }
  __syncthreads();

  if (sub < 4) {
    // q/k with RoPE: lo (sub even): out = a*c - p*s ; hi: out = a*c + p*s
    const bool hiw = (sub & 1);
    unsigned short* dst = (sub < 2) ? q_r : k_r;
    const int dbase = hiw ? 64 : 0;
#pragma unroll
    for (int fr = 0; fr < 2; ++fr)
#pragma unroll
      for (int fc = 0; fc < 2; ++fc)
#pragma unroll
        for (int reg = 0; reg < 16; ++reg) {
          int rl = fr * 32 + (reg & 3) + 8 * (reg >> 2) + 4 * hi;
          int r  = m0 + wm * 64 + rl;
          int s  = r & (S_DIM - 1), bb = r >> 11;
          int dp = fc * 32 + l31;
          float c  = cosT[(s << 6) + dp];
          float sn = sinT[(s << 6) + dp];
          float a  = acc[fr][fc][reg];
          float pv = pslot[(fr * 32 + fc * 16 + reg) * 64 + lane];
          float ov = hiw ? fmaf(a, c, pv * sn) : fmaf(a, c, -pv * sn);
          size_t ob = ((size_t)(bb * NHEAD + hh) * S_DIM + s) * HD_DIM
                      + dbase + dp;
          dst[ob] = f2bf(ov);
        }
  } else {
    // v: read back transposed, store v_t[bh][d][s] rows (16B per lane/iter)
    const int dbase = (sub - 4) * 64;
    const int bb = m0 >> 11;                       // block fully in one batch
    const int s0g = (m0 & (S_DIM - 1)) + wm * 64;
    unsigned short* vrow =
        v_t + ((size_t)(bb * NHEAD + hh) * HD_DIM + dbase) * S_DIM;
#pragma unroll
    for (int it = 0; it < 8; ++it) {
      int d = it * 8 + (lane >> 3);
      int c = lane & 7;
      int mb = (c ^ (d & 7)) * 8;                  // stored m-block
      const float* sp = slot + d * 64 + c * 8;     // 8 contiguous floats
      s16x8 ov;
#pragma unroll
      for (int e = 0; e < 8; ++e) ov[e] = (short)f2bf(sp[e]);
      *(s16x8*)(vrow + (size_t)d * S_DIM + s0g + mb) = ov;
    }
  }
}

// ------------------------------------------------- triple-buffered GEMM (B^T)
// Output projection; same 32x32x16 mainloop, plain fp32 epilogue.
__global__ __launch_bounds__(512, 1)
void gemm3b_kernel(const unsigned short* __restrict__ A,
                   const unsigned short* __restrict__ Bw,
                   float* __restrict__ C, int M, int N, int K) {
  __shared__ __align__(16) unsigned short lA[3][128 * 64];   // 3 x 16KB
  __shared__ __align__(16) unsigned short lB[3][256 * 64];   // 3 x 32KB
  const int tid  = threadIdx.x;
  const int wave = tid >> 6, lane = tid & 63;
  const int wm = wave >> 2, wn = wave & 3;       // 2M x 4N wave grid
  const int l31 = lane & 31, hi = lane >> 5;

  const int nbx = gridDim.x;
  const int id  = blockIdx.y * nbx + blockIdx.x;
  const int nwg = gridDim.x * gridDim.y;
  const int swz = (id & 7) * (nwg >> 3) + (id >> 3);
  const int m_tile = swz / nbx, n_tile = swz % nbx;
  const int m0 = m_tile * 128, n0 = n_tile * 256;

  f32x16 acc[2][2];
#pragma unroll
  for (int i = 0; i < 2; ++i)
#pragma unroll
    for (int j = 0; j < 2; ++j)
#pragma unroll
      for (int e = 0; e < 16; ++e) acc[i][j][e] = 0.f;

  const unsigned short* aP[2];
  const unsigned short* bP[4];
  int aD[2], bD[4];
#pragma unroll
  for (int i = 0; i < 2; ++i) {
    int cb = (i * 8 + wave) * 64 + lane;
    int cs = cb ^ ((cb >> 3) & 7);
    aP[i] = A + (size_t)(m0 + (cs >> 3)) * K + (cs & 7) * 8;
    aD[i] = cb * 8;
  }
#pragma unroll
  for (int i = 0; i < 4; ++i) {
    int cb = (i * 8 + wave) * 64 + lane;
    int cs = cb ^ ((cb >> 3) & 7);
    bP[i] = Bw + (size_t)(n0 + (cs >> 3)) * K + (cs & 7) * 8;
    bD[i] = cb * 8;
  }

  auto STAGE = [&](int buf, int t) {
    const int kt = t << 6;
#pragma unroll
    for (int i = 0; i < 2; ++i) gload_lds16(aP[i] + kt, &lA[buf][aD[i]]);
#pragma unroll
    for (int i = 0; i < 4; ++i) gload_lds16(bP[i] + kt, &lB[buf][bD[i]]);
  };

  const int rowA = wm * 8192 + l31 * 128;
  const int rowB = wn * 8192 + l31 * 128;
  int colx[4];
#pragma unroll
  for (int ks = 0; ks < 4; ++ks)
    colx[ks] = (ks * 32 + hi * 16) ^ ((l31 & 7) << 4);

  const int NT = K >> 6;
  STAGE(0, 0);
  if (NT > 1) {
    STAGE(1, 1);
    asm volatile("s_waitcnt vmcnt(6)" ::: "memory");
  } else {
    asm volatile("s_waitcnt vmcnt(0)" ::: "memory");
  }
  asm volatile("s_barrier" ::: "memory");

  for (int t = 0; t < NT; ++t) {
    const int cur = t % 3;
    const char* bA = (const char*)&lA[cur][0] + rowA;
    const char* bB = (const char*)&lB[cur][0] + rowB;

    bf16x8 af[4][2], bfr[4][2];
#pragma unroll
    for (int ks = 0; ks < 4; ++ks) {
      af[ks][0]  = load8((const unsigned short*)(bA + colx[ks]));
      af[ks][1]  = load8((const unsigned short*)(bA + colx[ks] + 4096));
      bfr[ks][0] = load8((const unsigned short*)(bB + colx[ks]));
      bfr[ks][1] = load8((const unsigned short*)(bB + colx[ks] + 4096));
    }

    if (t + 2 < NT) STAGE((t + 2) % 3, t + 2);

    __builtin_amdgcn_s_setprio(1);
#pragma unroll
    for (int ks = 0; ks < 4; ++ks)
#pragma unroll
      for (int fr = 0; fr < 2; ++fr)
#pragma unroll
        for (int fc = 0; fc < 2; ++fc)
          acc[fr][fc] = mfma32(af[ks][fr], bfr[ks][fc], acc[fr][fc]);
    __builtin_amdgcn_s_setprio(0);

    if (t + 2 < NT)
      asm volatile("s_waitcnt vmcnt(6)" ::: "memory");
    else if (t + 1 < NT)
      asm volatile("s_waitcnt vmcnt(0)" ::: "memory");
    asm volatile("s_barrier" ::: "memory");
  }

  // epilogue: 32x32 C/D layout col = lane&31, row = (reg&3)+8(reg>>2)+4*hi
#pragma unroll
  for (int fr = 0; fr < 2; ++fr)
#pragma unroll
    for (int fc = 0; fc < 2; ++fc)
#pragma unroll
      for (int reg = 0; reg < 16; ++reg) {
        int r   = m0 + wm * 64 + fr * 32 + (reg & 3) + 8 * (reg >> 2) + 4 * hi;
        int col = n0 + wn * 64 + fc * 32 + l31;
        C[(size_t)r * N + col] = acc[fr][fc][reg];
      }
}

// ---------------------------------------------------------------- attention
// 8-wave, KVBLK=128 staging (r22): grid (p=8, bh=32), 512 threads,
// 128 q-rows/block; pairing {p, 15-p} -> 17 kv128-tiles every block.
// Fragment addressing hoisted (r24).
__global__ __launch_bounds__(512, 1)
void attn_kernel(const unsigned short* __restrict__ qr,
                 const unsigned short* __restrict__ kr,
                 const unsigned short* __restrict__ vt,
                 unsigned short* __restrict__ out) {
  __shared__ __align__(16) unsigned short kbuf[2][128 * 128]; // 2 x 32KB
  __shared__ __align__(16) unsigned short vbuf[2][128 * 128]; // 2 x 32KB
  __shared__ __align__(16) unsigned short plds[8][16 * 72];   // 18KB
  const int p = blockIdx.x, bh = blockIdx.y;
  const int wave = threadIdx.x >> 6, lane = threadIdx.x & 63;
  const int b = bh >> 4, h = bh & 15;
  const int lg = lane >> 4, ll = lane & 15;
  const unsigned short* Qb = qr + (size_t)bh * S_DIM * HD_DIM;
  const unsigned short* Kb = kr + (size_t)bh * S_DIM * HD_DIM;
  const unsigned short* Vb = vt + (size_t)bh * HD_DIM * S_DIM;
  const float kE  = 0.12752792f;   // (1/sqrt(128)) * log2(e)
  const float THR = 11.5416f;      // 8 * log2(e)  (T13 threshold, k-domain)
  unsigned short* pw = &plds[wave][0];

  // hoisted per-lane fragment bases (byte offsets)
  const int xo = (ll & 7) << 4;
  int laneK[4], laneV[2];
#pragma unroll
  for (int kk = 0; kk < 4; ++kk)
    laneK[kk] = (ll * 256 + kk * 64 + lg * 16) ^ xo;
#pragma unroll
  for (int c = 0; c < 2; ++c)
    laneV[c] = (ll * 256 + c * 64 + lg * 16) ^ xo;

  for (int seg = 0; seg < 2; ++seg) {
    const int qt = seg ? (15 - p) : p;         // 128-row q-tile index
    const int qbase = qt * 128 + wave * 16;
    const int ntb = qt + 1;                    // kv128-tile count
    const int ntb64 = 2 * qt + 2;              // kv64-half count

    auto STAGE = [&](int buf, int t) {
      const int k0 = t * 128;
#pragma unroll
      for (int i = 0; i < 4; ++i) {
        int cb = (i * 8 + wave) * 64 + lane;   // 0..2047
        int cs = cb ^ ((cb >> 4) & 7);
        gload_lds16(Kb + (size_t)(k0 + (cs >> 4)) * HD_DIM + (cs & 15) * 8,
                    &kbuf[buf][cb * 8]);
      }
#pragma unroll
      for (int i = 0; i < 4; ++i) {
        int cb = (i * 8 + wave) * 64 + lane;
        int cs = cb ^ ((cb >> 4) & 7);
        gload_lds16(Vb + (size_t)(cs >> 4) * S_DIM + k0 + (cs & 15) * 8,
                    &vbuf[buf][cb * 8]);
      }
    };

    bf16x8 aq[4];
#pragma unroll
    for (int kk = 0; kk < 4; ++kk)
      aq[kk] = load8(Qb + (size_t)(qbase + ll) * HD_DIM + kk * 32 + lg * 8);

    float mk[4], lsum[4];
    f32x4 o[8];
#pragma unroll
    for (int j = 0; j < 4; ++j) { mk[j] = -1e30f; lsum[j] = 0.f; }
#pragma unroll
    for (int f = 0; f < 8; ++f) o[f] = (f32x4){0.f, 0.f, 0.f, 0.f};

    STAGE(0, 0);
    __syncthreads();   // implicit vmcnt(0) drain

    for (int t = 0; t < ntb; ++t) {
      const int cur = t & 1;
      if (t + 1 < ntb) STAGE(cur ^ 1, t + 1);  // full-tile latency cover
      const char* kb = (const char*)&kbuf[cur][0];
      const char* vb = (const char*)&vbuf[cur][0];

#pragma unroll
      for (int half = 0; half < 2; ++half) {
        const int th = 2 * t + half;           // kv64-half index
        const int k0h = th * 64;
        const bool maskt = (th >= ntb64 - 2);  // block-uniform

        f32x4 s[4];
#pragma unroll
        for (int kf = 0; kf < 4; ++kf) s[kf] = (f32x4){0.f, 0.f, 0.f, 0.f};
        __builtin_amdgcn_s_setprio(1);
#pragma unroll
        for (int kf = 0; kf < 4; ++kf)
#pragma unroll
          for (int kk = 0; kk < 4; ++kk)
            s[kf] = mfma_bf16(
                aq[kk],
                load8((const unsigned short*)(kb + laneK[kk] + half * 16384 +
                                              kf * 4096)),
                s[kf]);
        __builtin_amdgcn_s_setprio(0);

        if (maskt) {
#pragma unroll
          for (int kf = 0; kf < 4; ++kf) {
            int kcol = k0h + kf * 16 + ll;
#pragma unroll
            for (int j = 0; j < 4; ++j) {
              int qrow = qbase + lg * 4 + j;
              if (kcol > qrow) s[kf][j] = -1e31f;
            }
          }
        }

        float pmax[4];
        bool ok = true;
#pragma unroll
        for (int j = 0; j < 4; ++j) {
          pmax[j] = fmaxf(fmaxf(s[0][j], s[1][j]), fmaxf(s[2][j], s[3][j]));
          ok = ok && (pmax[j] * kE - mk[j] <= THR);
        }
        if (!__all(ok)) {                      // rare: ~once per segment
#pragma unroll
          for (int j = 0; j < 4; ++j) {
            float rm = pmax[j] * kE;
#pragma unroll
            for (int off = 1; off < 16; off <<= 1)
              rm = fmaxf(rm, __shfl_xor(rm, off, 64));
            rm = fmaxf(rm, mk[j]);
            float corr = exp2f(mk[j] - rm);
            mk[j] = rm;
            lsum[j] *= corr;
#pragma unroll
            for (int f = 0; f < 8; ++f) o[f][j] *= corr;
          }
        }
#pragma unroll
        for (int j = 0; j < 4; ++j) {
          int prow = (lg * 4 + j) * 72;
#pragma unroll
          for (int kf = 0; kf < 4; ++kf) {
            float e = exp2f(fmaf(s[kf][j], kE, -mk[j]));
            lsum[j] += e;
            pw[prow + kf * 16 + ll] = f2bf(e);
          }
        }

        bf16x8 pa0 = load8(&pw[ll * 72 + lg * 8]);
        bf16x8 pa1 = load8(&pw[ll * 72 + 32 + lg * 8]);
        __builtin_amdgcn_s_setprio(1);
#pragma unroll
        for (int f = 0; f < 8; ++f) {
          o[f] = mfma_bf16(
              pa0,
              load8((const unsigned short*)(vb + laneV[0] + f * 4096 +
                                            half * 128)),
              o[f]);
          o[f] = mfma_bf16(
              pa1,
              load8((const unsigned short*)(vb + laneV[1] + f * 4096 +
                                            half * 128)),
              o[f]);
        }
        __builtin_amdgcn_s_setprio(0);
      }

      __syncthreads();   // once per 128-tile: drains staged vmcnt + dbuf guard
    }

#pragma unroll
    for (int j = 0; j < 4; ++j) {
      float l = lsum[j];
#pragma unroll
      for (int off = 1; off < 16; off <<= 1) l += __shfl_xor(l, off, 64);
      lsum[j] = 1.0f / l;
    }
#pragma unroll
    for (int f = 0; f < 8; ++f)
#pragma unroll
      for (int j = 0; j < 4; ++j) {
        int srow = qbase + lg * 4 + j;
        out[((size_t)(b * S_DIM + srow)) * H_DIM + h * HD_DIM + f * 16 + ll] =
            f2bf(o[f][j] * lsum[j]);
      }
  }
}

// ---------------------------------------------------------------- launch
extern "C" void kernel_launch(void* const* d_in, const int* in_sizes, int n_in,
                              void* d_out, int out_size, void* d_ws, size_t ws_size,
                              hipStream_t stream) {
  (void)in_sizes; (void)n_in; (void)out_size; (void)ws_size;
  const float* hidden = (const float*)d_in[0];
  const float* wqkv   = (const float*)d_in[1];
  const float* wo     = (const float*)d_in[2];
  char* ws = (char*)d_ws;
  unsigned short* hid_b  = (unsigned short*)(ws);               // 16,777,216
  unsigned short* wqkv_b = (unsigned short*)(ws + 16777216);    // 25,165,824
  unsigned short* wo_b   = (unsigned short*)(ws + 41943040);    //  8,388,608
  unsigned short* q_r    = (unsigned short*)(ws + 100663296);   // 16,777,216
  unsigned short* k_r    = (unsigned short*)(ws + 117440512);   // 16,777,216
  unsigned short* v_t    = (unsigned short*)(ws + 134217728);   // 16,777,216
  unsigned short* attn   = (unsigned short*)(ws + 150994944);   // 16,777,216
  float* cosT            = (float*)(ws + 167772160);            //    524,288
  float* sinT            = (float*)(ws + 168296448);            //    524,288

  prep_kernel<<<2048, 256, 0, stream>>>(hidden, wqkv, wo, hid_b, wqkv_b, wo_b,
                                        cosT, sinT);

  // QKV projection + fused RoPE + fused V-transpose: grid 24x32 = 3 rounds
  gemm_qkv_kernel<<<dim3(O3 / 256, BS / 128), 512, 0, stream>>>(
      hid_b, wqkv_b, q_r, k_r, v_t, cosT, sinT, BS, O3, H_DIM);

  // attention: 8-wave blocks, KVBLK=128 staging, grid 8x32 = 256 = 1/CU
  attn_kernel<<<dim3(8, 32), 512, 0, stream>>>(q_r, k_r, v_t, attn);

  // output projection: grid 8x32 = 256 = exactly 1 round; chunked map
  gemm3b_kernel<<<dim3(H_DIM / 256, BS / 128), 512, 0, stream>>>(
      attn, wo_b, (float*)d_out, BS, H_DIM, H_DIM);
}

// Round 28
// 238.108 us; speedup vs baseline: 1.1084x; 1.1084x over previous
//
#include <hip/hip_runtime.h>
#include <hip/hip_bf16.h>
#include <cstdint>
#include <cstddef>

// Problem constants
#define S_DIM 2048
#define H_DIM 2048
#define NHEAD 16
#define HD_DIM 128
#define O3    6144   // 3*H
#define BS    4096   // B*S
#define NBH   32     // B*NHEAD

typedef short  s16x4  __attribute__((ext_vector_type(4)));
typedef short  s16x8  __attribute__((ext_vector_type(8)));
typedef __bf16 bf16x8 __attribute__((ext_vector_type(8)));
typedef float  f32x4  __attribute__((ext_vector_type(4)));

__device__ __forceinline__ unsigned short f2bf(float f) {
  unsigned int b = __float_as_uint(f);
  b += 0x7FFFu + ((b >> 16) & 1u);          // round-to-nearest-even
  return (unsigned short)(b >> 16);
}
__device__ __forceinline__ float bf2f(unsigned short u) {
  return __uint_as_float(((unsigned int)u) << 16);
}
__device__ __forceinline__ bf16x8 load8(const unsigned short* p) {
  s16x8 r = *(const s16x8*)p;
  return __builtin_bit_cast(bf16x8, r);
}
__device__ __forceinline__ f32x4 mfma_bf16(bf16x8 a, bf16x8 b, f32x4 c) {
  return __builtin_amdgcn_mfma_f32_16x16x32_bf16(a, b, c, 0, 0, 0);
}
__device__ __forceinline__ void gload_lds16(const void* g, void* l) {
  __builtin_amdgcn_global_load_lds(
      (__attribute__((address_space(1))) unsigned int*)g,
      (__attribute__((address_space(3))) unsigned int*)l, 16, 0, 0);
}

// -------------------------------------------------- fused prep (one launch)
__global__ void prep_kernel(const float* __restrict__ hid,
                            const float* __restrict__ wqkv,
                            const float* __restrict__ wo,
                            unsigned short* __restrict__ hid_b,
                            unsigned short* __restrict__ wqkv_b,
                            unsigned short* __restrict__ wo_b,
                            float* __restrict__ cosT,
                            float* __restrict__ sinT) {
  const int nA = 2097152, nB = 3145728, nC = 1048576, nD = 131072;
  const int total = nA + nB + nC + nD;
  int stride = gridDim.x * blockDim.x;
  for (int i = blockIdx.x * blockDim.x + threadIdx.x; i < total; i += stride) {
    if (i < nA + nB + nC) {
      const float* src; unsigned short* dst; int j;
      if (i < nA)            { src = hid;  dst = hid_b;  j = i; }
      else if (i < nA + nB)  { src = wqkv; dst = wqkv_b; j = i - nA; }
      else                   { src = wo;   dst = wo_b;   j = i - nA - nB; }
      float4 v = ((const float4*)src)[j];
      ushort4 o;
      o.x = f2bf(v.x); o.y = f2bf(v.y); o.z = f2bf(v.z); o.w = f2bf(v.w);
      ((ushort4*)dst)[j] = o;
    } else {
      int idx = i - nA - nB - nC;          // 0..131071 = s*64 + d
      int s = idx >> 6, d = idx & 63;
      float inv = expf(-((float)d / 64.0f) * 9.210340371976184f);
      float ang = (float)s * inv;
      float sn, cs;
      sincosf(ang, &sn, &cs);
      cosT[idx] = cs;
      sinT[idx] = sn;
    }
  }
}

// ------------------------------------- QKV GEMM with fused RoPE + V-transpose
// Mainloop = proven gemm3b (hoisted fragment addressing, r24; 16x16x32 MFMA —
// r27 ledger: 32x32 frag on 128B-stride rows is an unavoidable 8-way LDS
// conflict, regressed 21%). Epilogue: q/k waves exchange halves via LDS
// (pair = wave^1) + RoPE; v waves write transpose layout and store v_t
// directly (r25).
__global__ __launch_bounds__(512, 1)
void gemm_qkv_kernel(const unsigned short* __restrict__ A,
                     const unsigned short* __restrict__ Bw,
                     unsigned short* __restrict__ q_r,
                     unsigned short* __restrict__ k_r,
                     unsigned short* __restrict__ v_t,
                     const float* __restrict__ cosT,
                     const float* __restrict__ sinT,
                     int M, int N, int K) {
  __shared__ __align__(16) unsigned short lA[3][128 * 64];   // 3 x 16KB
  __shared__ __align__(16) unsigned short lB[3][256 * 64];   // 3 x 32KB
  const int tid  = threadIdx.x;
  const int wave = tid >> 6, lane = tid & 63;
  const int wm = wave >> 2, wn = wave & 3;       // 2M x 4N wave grid
  const int lg = lane >> 4, ll = lane & 15;

  // L2-aware XCD map (r11): grid 24(n) x 32(m)
  const int nbx = gridDim.x;
  const int id  = blockIdx.y * nbx + blockIdx.x;
  const int k8 = id & 7, q8 = id >> 3;
  const int ng = q8 >> 5, r8 = q8 & 31;
  const int m_tile = (k8 >> 1) * 8 + (r8 & 7);
  const int n_tile = (k8 & 1) * 12 + ng * 4 + (r8 >> 3);
  const int m0 = m_tile * 128, n0 = n_tile * 256;

  f32x4 acc[4][4];
#pragma unroll
  for (int i = 0; i < 4; ++i)
#pragma unroll
    for (int j = 0; j < 4; ++j) acc[i][j] = (f32x4){0.f, 0.f, 0.f, 0.f};

  const unsigned short* aP[2];
  const unsigned short* bP[4];
  int aD[2], bD[4];
#pragma unroll
  for (int i = 0; i < 2; ++i) {
    int cb = (i * 8 + wave) * 64 + lane;
    int cs = cb ^ ((cb >> 3) & 7);
    aP[i] = A + (size_t)(m0 + (cs >> 3)) * K + (cs & 7) * 8;
    aD[i] = cb * 8;
  }
#pragma unroll
  for (int i = 0; i < 4; ++i) {
    int cb = (i * 8 + wave) * 64 + lane;
    int cs = cb ^ ((cb >> 3) & 7);
    bP[i] = Bw + (size_t)(n0 + (cs >> 3)) * K + (cs & 7) * 8;
    bD[i] = cb * 8;
  }

  auto STAGE = [&](int buf, int t) {
    const int kt = t << 6;
#pragma unroll
    for (int i = 0; i < 2; ++i) gload_lds16(aP[i] + kt, &lA[buf][aD[i]]);
#pragma unroll
    for (int i = 0; i < 4; ++i) gload_lds16(bP[i] + kt, &lB[buf][bD[i]]);
  };

  // hoisted per-lane fragment bases (byte offsets)
  const int xo = (ll & 7) << 4;
  const int laneA0 = wm * 8192 + ((ll * 128 + lg * 16) ^ xo);
  const int laneA1 = wm * 8192 + ((ll * 128 + 64 + lg * 16) ^ xo);
  const int laneB0 = wn * 8192 + ((ll * 128 + lg * 16) ^ xo);
  const int laneB1 = wn * 8192 + ((ll * 128 + 64 + lg * 16) ^ xo);

  const int NT = K >> 6;
  STAGE(0, 0);
  STAGE(1, 1);
  asm volatile("s_waitcnt vmcnt(6)" ::: "memory");
  asm volatile("s_barrier" ::: "memory");

  for (int t = 0; t < NT; ++t) {
    const int cur = t % 3;
    const char* pA0 = (const char*)&lA[cur][0] + laneA0;
    const char* pA1 = (const char*)&lA[cur][0] + laneA1;
    const char* pB0 = (const char*)&lB[cur][0] + laneB0;
    const char* pB1 = (const char*)&lB[cur][0] + laneB1;

    bf16x8 af[4][2], bfr[2][2][2];
#pragma unroll
    for (int fq = 0; fq < 4; ++fq) {
      af[fq][0] = load8((const unsigned short*)(pA0 + fq * 2048));
      af[fq][1] = load8((const unsigned short*)(pA1 + fq * 2048));
    }
#pragma unroll
    for (int nh = 0; nh < 2; ++nh)
#pragma unroll
      for (int fq = 0; fq < 2; ++fq) {
        bfr[nh][fq][0] = load8((const unsigned short*)(pB0 + nh * 4096 + fq * 2048));
        bfr[nh][fq][1] = load8((const unsigned short*)(pB1 + nh * 4096 + fq * 2048));
      }

    if (t + 2 < NT) STAGE((t + 2) % 3, t + 2);

    __builtin_amdgcn_s_setprio(1);
#pragma unroll
    for (int nh = 0; nh < 2; ++nh)
#pragma unroll
      for (int fq = 0; fq < 4; ++fq)
#pragma unroll
        for (int gq = 0; gq < 2; ++gq)
#pragma unroll
          for (int kk = 0; kk < 2; ++kk)
            acc[fq][nh * 2 + gq] =
                mfma_bf16(af[fq][kk], bfr[nh][gq][kk], acc[fq][nh * 2 + gq]);
    __builtin_amdgcn_s_setprio(0);

    if (t + 2 < NT)
      asm volatile("s_waitcnt vmcnt(6)" ::: "memory");
    else if (t + 1 < NT)
      asm volatile("s_waitcnt vmcnt(0)" ::: "memory");
    asm volatile("s_barrier" ::: "memory");
  }

  // ---- fused epilogue (after final barrier: LDS reuse is safe) ----
  const int g   = n_tile * 4 + wn;
  const int sub = g % 6, hh = g / 6;
  float* slot = (wave < 3) ? (float*)&lA[wave][0]
                           : (float*)&lB[0][0] + (size_t)(wave - 3) * 4096;
  const float* pslot = ((wave ^ 1) < 3)
                           ? (const float*)&lA[wave ^ 1][0]
                           : (const float*)&lB[0][0] + (size_t)((wave ^ 1) - 3) * 4096;

  if (sub < 4) {
    // exchange layout [idx][lane] (conflict-free)
#pragma unroll
    for (int fm = 0; fm < 4; ++fm)
#pragma unroll
      for (int fn = 0; fn < 4; ++fn)
#pragma unroll
        for (int j = 0; j < 4; ++j)
          slot[(fm * 16 + fn * 4 + j) * 64 + lane] = acc[fm][fn][j];
  } else {
    // transpose layout [d][m ^ ((d&7)<<3)] (bijective per row)
#pragma unroll
    for (int fm = 0; fm < 4; ++fm)
#pragma unroll
      for (int fn = 0; fn < 4; ++fn)
#pragma unroll
        for (int j = 0; j < 4; ++j) {
          int d = fn * 16 + ll;
          int m = fm * 16 + lg * 4 + j;
          slot[d * 64 + (m ^ ((d & 7) << 3))] = acc[fm][fn][j];
        }
  }
  __syncthreads();

  if (sub < 4) {
    // q/k with RoPE: lo (sub even): out = a*c - p*s ; hi: out = a*c + p*s
    const bool hi = (sub & 1);
    unsigned short* dst = (sub < 2) ? q_r : k_r;
    const int dbase = hi ? 64 : 0;
#pragma unroll
    for (int fm = 0; fm < 4; ++fm)
#pragma unroll
      for (int fn = 0; fn < 4; ++fn)
#pragma unroll
        for (int j = 0; j < 4; ++j) {
          int r  = m0 + wm * 64 + fm * 16 + lg * 4 + j;
          int s  = r & (S_DIM - 1), bb = r >> 11;
          int dp = fn * 16 + ll;
          float c  = cosT[(s << 6) + dp];
          float sn = sinT[(s << 6) + dp];
          float a  = acc[fm][fn][j];
          float pv = pslot[(fm * 16 + fn * 4 + j) * 64 + lane];
          float ov = hi ? fmaf(a, c, pv * sn) : fmaf(a, c, -pv * sn);
          size_t ob = ((size_t)(bb * NHEAD + hh) * S_DIM + s) * HD_DIM
                      + dbase + dp;
          dst[ob] = f2bf(ov);
        }
  } else {
    // v: read back transposed, store v_t[bh][d][s] rows (16B per lane/iter)
    const int dbase = (sub - 4) * 64;
    const int bb = m0 >> 11;                       // block fully in one batch
    const int s0g = (m0 & (S_DIM - 1)) + wm * 64;
    unsigned short* vrow =
        v_t + ((size_t)(bb * NHEAD + hh) * HD_DIM + dbase) * S_DIM;
#pragma unroll
    for (int it = 0; it < 8; ++it) {
      int d = it * 8 + (lane >> 3);
      int c = lane & 7;
      int mb = (c ^ (d & 7)) * 8;                  // stored m-block
      const float* sp = slot + d * 64 + c * 8;     // 8 contiguous floats
      s16x8 ov;
#pragma unroll
      for (int e = 0; e < 8; ++e) ov[e] = (short)f2bf(sp[e]);
      *(s16x8*)(vrow + (size_t)d * S_DIM + s0g + mb) = ov;
    }
  }
}

// ------------------------------------------------- triple-buffered GEMM (B^T)
// Output projection (16x16x32, hoisted addressing; 256 blocks = 1 round).
__global__ __launch_bounds__(512, 1)
void gemm3b_kernel(const unsigned short* __restrict__ A,
                   const unsigned short* __restrict__ Bw,
                   float* __restrict__ C, int M, int N, int K) {
  __shared__ __align__(16) unsigned short lA[3][128 * 64];   // 3 x 16KB
  __shared__ __align__(16) unsigned short lB[3][256 * 64];   // 3 x 32KB
  const int tid  = threadIdx.x;
  const int wave = tid >> 6, lane = tid & 63;
  const int wm = wave >> 2, wn = wave & 3;       // 2M x 4N wave grid
  const int lg = lane >> 4, ll = lane & 15;

  const int nbx = gridDim.x;
  const int id  = blockIdx.y * nbx + blockIdx.x;
  const int nwg = gridDim.x * gridDim.y;
  const int swz = (id & 7) * (nwg >> 3) + (id >> 3);
  const int m_tile = swz / nbx, n_tile = swz % nbx;
  const int m0 = m_tile * 128, n0 = n_tile * 256;

  f32x4 acc[4][4];
#pragma unroll
  for (int i = 0; i < 4; ++i)
#pragma unroll
    for (int j = 0; j < 4; ++j) acc[i][j] = (f32x4){0.f, 0.f, 0.f, 0.f};

  const unsigned short* aP[2];
  const unsigned short* bP[4];
  int aD[2], bD[4];
#pragma unroll
  for (int i = 0; i < 2; ++i) {
    int cb = (i * 8 + wave) * 64 + lane;
    int cs = cb ^ ((cb >> 3) & 7);
    aP[i] = A + (size_t)(m0 + (cs >> 3)) * K + (cs & 7) * 8;
    aD[i] = cb * 8;
  }
#pragma unroll
  for (int i = 0; i < 4; ++i) {
    int cb = (i * 8 + wave) * 64 + lane;
    int cs = cb ^ ((cb >> 3) & 7);
    bP[i] = Bw + (size_t)(n0 + (cs >> 3)) * K + (cs & 7) * 8;
    bD[i] = cb * 8;
  }

  auto STAGE = [&](int buf, int t) {
    const int kt = t << 6;
#pragma unroll
    for (int i = 0; i < 2; ++i) gload_lds16(aP[i] + kt, &lA[buf][aD[i]]);
#pragma unroll
    for (int i = 0; i < 4; ++i) gload_lds16(bP[i] + kt, &lB[buf][bD[i]]);
  };

  const int xo = (ll & 7) << 4;
  const int laneA0 = wm * 8192 + ((ll * 128 + lg * 16) ^ xo);
  const int laneA1 = wm * 8192 + ((ll * 128 + 64 + lg * 16) ^ xo);
  const int laneB0 = wn * 8192 + ((ll * 128 + lg * 16) ^ xo);
  const int laneB1 = wn * 8192 + ((ll * 128 + 64 + lg * 16) ^ xo);

  const int NT = K >> 6;
  STAGE(0, 0);
  if (NT > 1) {
    STAGE(1, 1);
    asm volatile("s_waitcnt vmcnt(6)" ::: "memory");
  } else {
    asm volatile("s_waitcnt vmcnt(0)" ::: "memory");
  }
  asm volatile("s_barrier" ::: "memory");

  for (int t = 0; t < NT; ++t) {
    const int cur = t % 3;
    const char* pA0 = (const char*)&lA[cur][0] + laneA0;
    const char* pA1 = (const char*)&lA[cur][0] + laneA1;
    const char* pB0 = (const char*)&lB[cur][0] + laneB0;
    const char* pB1 = (const char*)&lB[cur][0] + laneB1;

    bf16x8 af[4][2], bfr[2][2][2];
#pragma unroll
    for (int fq = 0; fq < 4; ++fq) {
      af[fq][0] = load8((const unsigned short*)(pA0 + fq * 2048));
      af[fq][1] = load8((const unsigned short*)(pA1 + fq * 2048));
    }
#pragma unroll
    for (int nh = 0; nh < 2; ++nh)
#pragma unroll
      for (int fq = 0; fq < 2; ++fq) {
        bfr[nh][fq][0] = load8((const unsigned short*)(pB0 + nh * 4096 + fq * 2048));
        bfr[nh][fq][1] = load8((const unsigned short*)(pB1 + nh * 4096 + fq * 2048));
      }

    if (t + 2 < NT) STAGE((t + 2) % 3, t + 2);

    __builtin_amdgcn_s_setprio(1);
#pragma unroll
    for (int nh = 0; nh < 2; ++nh)
#pragma unroll
      for (int fq = 0; fq < 4; ++fq)
#pragma unroll
        for (int gq = 0; gq < 2; ++gq)
#pragma unroll
          for (int kk = 0; kk < 2; ++kk)
            acc[fq][nh * 2 + gq] =
                mfma_bf16(af[fq][kk], bfr[nh][gq][kk], acc[fq][nh * 2 + gq]);
    __builtin_amdgcn_s_setprio(0);

    if (t + 2 < NT)
      asm volatile("s_waitcnt vmcnt(6)" ::: "memory");
    else if (t + 1 < NT)
      asm volatile("s_waitcnt vmcnt(0)" ::: "memory");
    asm volatile("s_barrier" ::: "memory");
  }

#pragma unroll
  for (int fm = 0; fm < 4; ++fm)
#pragma unroll
    for (int fn = 0; fn < 4; ++fn)
#pragma unroll
      for (int j = 0; j < 4; ++j) {
        int r   = m0 + wm * 64 + fm * 16 + lg * 4 + j;
        int col = n0 + wn * 64 + fn * 16 + ll;
        C[(size_t)r * N + col] = acc[fm][fn][j];
      }
}

// ---------------------------------------------------------------- attention
// 8-wave, KVBLK=128 staging (r22): grid (p=8, bh=32), 512 threads,
// 128 q-rows/block; pairing {p, 15-p} -> 17 kv128-tiles every block.
// Fragment addressing hoisted (r24).
__global__ __launch_bounds__(512, 1)
void attn_kernel(const unsigned short* __restrict__ qr,
                 const unsigned short* __restrict__ kr,
                 const unsigned short* __restrict__ vt,
                 unsigned short* __restrict__ out) {
  __shared__ __align__(16) unsigned short kbuf[2][128 * 128]; // 2 x 32KB
  __shared__ __align__(16) unsigned short vbuf[2][128 * 128]; // 2 x 32KB
  __shared__ __align__(16) unsigned short plds[8][16 * 72];   // 18KB
  const int p = blockIdx.x, bh = blockIdx.y;
  const int wave = threadIdx.x >> 6, lane = threadIdx.x & 63;
  const int b = bh >> 4, h = bh & 15;
  const int lg = lane >> 4, ll = lane & 15;
  const unsigned short* Qb = qr + (size_t)bh * S_DIM * HD_DIM;
  const unsigned short* Kb = kr + (size_t)bh * S_DIM * HD_DIM;
  const unsigned short* Vb = vt + (size_t)bh * HD_DIM * S_DIM;
  const float kE  = 0.12752792f;   // (1/sqrt(128)) * log2(e)
  const float THR = 11.5416f;      // 8 * log2(e)  (T13 threshold, k-domain)
  unsigned short* pw = &plds[wave][0];

  // hoisted per-lane fragment bases (byte offsets)
  const int xo = (ll & 7) << 4;
  int laneK[4], laneV[2];
#pragma unroll
  for (int kk = 0; kk < 4; ++kk)
    laneK[kk] = (ll * 256 + kk * 64 + lg * 16) ^ xo;
#pragma unroll
  for (int c = 0; c < 2; ++c)
    laneV[c] = (ll * 256 + c * 64 + lg * 16) ^ xo;

  for (int seg = 0; seg < 2; ++seg) {
    const int qt = seg ? (15 - p) : p;         // 128-row q-tile index
    const int qbase = qt * 128 + wave * 16;
    const int ntb = qt + 1;                    // kv128-tile count
    const int ntb64 = 2 * qt + 2;              // kv64-half count

    auto STAGE = [&](int buf, int t) {
      const int k0 = t * 128;
#pragma unroll
      for (int i = 0; i < 4; ++i) {
        int cb = (i * 8 + wave) * 64 + lane;   // 0..2047
        int cs = cb ^ ((cb >> 4) & 7);
        gload_lds16(Kb + (size_t)(k0 + (cs >> 4)) * HD_DIM + (cs & 15) * 8,
                    &kbuf[buf][cb * 8]);
      }
#pragma unroll
      for (int i = 0; i < 4; ++i) {
        int cb = (i * 8 + wave) * 64 + lane;
        int cs = cb ^ ((cb >> 4) & 7);
        gload_lds16(Vb + (size_t)(cs >> 4) * S_DIM + k0 + (cs & 15) * 8,
                    &vbuf[buf][cb * 8]);
      }
    };

    bf16x8 aq[4];
#pragma unroll
    for (int kk = 0; kk < 4; ++kk)
      aq[kk] = load8(Qb + (size_t)(qbase + ll) * HD_DIM + kk * 32 + lg * 8);

    float mk[4], lsum[4];
    f32x4 o[8];
#pragma unroll
    for (int j = 0; j < 4; ++j) { mk[j] = -1e30f; lsum[j] = 0.f; }
#pragma unroll
    for (int f = 0; f < 8; ++f) o[f] = (f32x4){0.f, 0.f, 0.f, 0.f};

    STAGE(0, 0);
    __syncthreads();   // implicit vmcnt(0) drain

    for (int t = 0; t < ntb; ++t) {
      const int cur = t & 1;
      if (t + 1 < ntb) STAGE(cur ^ 1, t + 1);  // full-tile latency cover
      const char* kb = (const char*)&kbuf[cur][0];
      const char* vb = (const char*)&vbuf[cur][0];

#pragma unroll
      for (int half = 0; half < 2; ++half) {
        const int th = 2 * t + half;           // kv64-half index
        const int k0h = th * 64;
        const bool maskt = (th >= ntb64 - 2);  // block-uniform

        f32x4 s[4];
#pragma unroll
        for (int kf = 0; kf < 4; ++kf) s[kf] = (f32x4){0.f, 0.f, 0.f, 0.f};
        __builtin_amdgcn_s_setprio(1);
#pragma unroll
        for (int kf = 0; kf < 4; ++kf)
#pragma unroll
          for (int kk = 0; kk < 4; ++kk)
            s[kf] = mfma_bf16(
                aq[kk],
                load8((const unsigned short*)(kb + laneK[kk] + half * 16384 +
                                              kf * 4096)),
                s[kf]);
        __builtin_amdgcn_s_setprio(0);

        if (maskt) {
#pragma unroll
          for (int kf = 0; kf < 4; ++kf) {
            int kcol = k0h + kf * 16 + ll;
#pragma unroll
            for (int j = 0; j < 4; ++j) {
              int qrow = qbase + lg * 4 + j;
              if (kcol > qrow) s[kf][j] = -1e31f;
            }
          }
        }

        float pmax[4];
        bool ok = true;
#pragma unroll
        for (int j = 0; j < 4; ++j) {
          pmax[j] = fmaxf(fmaxf(s[0][j], s[1][j]), fmaxf(s[2][j], s[3][j]));
          ok = ok && (pmax[j] * kE - mk[j] <= THR);
        }
        if (!__all(ok)) {                      // rare: ~once per segment
#pragma unroll
          for (int j = 0; j < 4; ++j) {
            float rm = pmax[j] * kE;
#pragma unroll
            for (int off = 1; off < 16; off <<= 1)
              rm = fmaxf(rm, __shfl_xor(rm, off, 64));
            rm = fmaxf(rm, mk[j]);
            float corr = exp2f(mk[j] - rm);
            mk[j] = rm;
            lsum[j] *= corr;
#pragma unroll
            for (int f = 0; f < 8; ++f) o[f][j] *= corr;
          }
        }
#pragma unroll
        for (int j = 0; j < 4; ++j) {
          int prow = (lg * 4 + j) * 72;
#pragma unroll
          for (int kf = 0; kf < 4; ++kf) {
            float e = exp2f(fmaf(s[kf][j], kE, -mk[j]));
            lsum[j] += e;
            pw[prow + kf * 16 + ll] = f2bf(e);
          }
        }

        bf16x8 pa0 = load8(&pw[ll * 72 + lg * 8]);
        bf16x8 pa1 = load8(&pw[ll * 72 + 32 + lg * 8]);
        __builtin_amdgcn_s_setprio(1);
#pragma unroll
        for (int f = 0; f < 8; ++f) {
          o[f] = mfma_bf16(
              pa0,
              load8((const unsigned short*)(vb + laneV[0] + f * 4096 +
                                            half * 128)),
              o[f]);
          o[f] = mfma_bf16(
              pa1,
              load8((const unsigned short*)(vb + laneV[1] + f * 4096 +
                                            half * 128)),
              o[f]);
        }
        __builtin_amdgcn_s_setprio(0);
      }

      __syncthreads();   // once per 128-tile: drains staged vmcnt + dbuf guard
    }

#pragma unroll
    for (int j = 0; j < 4; ++j) {
      float l = lsum[j];
#pragma unroll
      for (int off = 1; off < 16; off <<= 1) l += __shfl_xor(l, off, 64);
      lsum[j] = 1.0f / l;
    }
#pragma unroll
    for (int f = 0; f < 8; ++f)
#pragma unroll
      for (int j = 0; j < 4; ++j) {
        int srow = qbase + lg * 4 + j;
        out[((size_t)(b * S_DIM + srow)) * H_DIM + h * HD_DIM + f * 16 + ll] =
            f2bf(o[f][j] * lsum[j]);
      }
  }
}

// ---------------------------------------------------------------- launch
extern "C" void kernel_launch(void* const* d_in, const int* in_sizes, int n_in,
                              void* d_out, int out_size, void* d_ws, size_t ws_size,
                              hipStream_t stream) {
  (void)in_sizes; (void)n_in; (void)out_size; (void)ws_size;
  const float* hidden = (const float*)d_in[0];
  const float* wqkv   = (const float*)d_in[1];
  const float* wo     = (const float*)d_in[2];
  char* ws = (char*)d_ws;
  unsigned short* hid_b  = (unsigned short*)(ws);               // 16,777,216
  unsigned short* wqkv_b = (unsigned short*)(ws + 16777216);    // 25,165,824
  unsigned short* wo_b   = (unsigned short*)(ws + 41943040);    //  8,388,608
  unsigned short* q_r    = (unsigned short*)(ws + 100663296);   // 16,777,216
  unsigned short* k_r    = (unsigned short*)(ws + 117440512);   // 16,777,216
  unsigned short* v_t    = (unsigned short*)(ws + 134217728);   // 16,777,216
  unsigned short* attn   = (unsigned short*)(ws + 150994944);   // 16,777,216
  float* cosT            = (float*)(ws + 167772160);            //    524,288
  float* sinT            = (float*)(ws + 168296448);            //    524,288

  prep_kernel<<<2048, 256, 0, stream>>>(hidden, wqkv, wo, hid_b, wqkv_b, wo_b,
                                        cosT, sinT);

  // QKV projection + fused RoPE + fused V-transpose: grid 24x32 = 3 rounds
  gemm_qkv_kernel<<<dim3(O3 / 256, BS / 128), 512, 0, stream>>>(
      hid_b, wqkv_b, q_r, k_r, v_t, cosT, sinT, BS, O3, H_DIM);

  // attention: 8-wave blocks, KVBLK=128 staging, grid 8x32 = 256 = 1/CU
  attn_kernel<<<dim3(8, 32), 512, 0, stream>>>(q_r, k_r, v_t, attn);

  // output projection: grid 8x32 = 256 = exactly 1 round; chunked map
  gemm3b_kernel<<<dim3(H_DIM / 256, BS / 128), 512, 0, stream>>>(
      attn, wo_b, (float*)d_out, BS, H_DIM, H_DIM);
}